// Round 5
// baseline (510.823 us; speedup 1.0000x reference)
//
#include <hip/hip_runtime.h>

// ---------------------------------------------------------------------------
// GAT edge classifier, MI355X.
//   CSR build (deg hist -> scan -> scatter)            [int atomics only]
//   pack: x -> (xh, xl) bf16 split; W1,W2 -> transposed bf16 splits
//   GEMM  (templated NF): block = 64 rows x full N, wave = 16 rows x 16*NF,
//         A fetched once, B L2-broadcast, 3-term bf16 split -> bf16 out
//   attn node dots (bf16 reads)
//   gather1: 1 wave/node, 8B/lane, fused p=exp(lrelu(.)), 2-edge ILP
//   GEMM2 -> xp2b; attn2; gather2 (4-edge groups/wave, fused uv=h2@Wc)
//   classify: out[e] = u[row] + v[col] + bc
// ---------------------------------------------------------------------------

#define NEG 0.2f

typedef __attribute__((ext_vector_type(8))) short bf16x8;
typedef __attribute__((ext_vector_type(4))) float f32x4;

__device__ __forceinline__ unsigned short f2bf(float f) {
    unsigned int u = __float_as_uint(f);
    unsigned int r = (u + 0x7FFFu + ((u >> 16) & 1u)) >> 16;   // RNE
    return (unsigned short)r;
}
__device__ __forceinline__ float bf2f(unsigned short h) {
    return __uint_as_float(((unsigned int)h) << 16);
}
__device__ __forceinline__ float bflo(unsigned int u) { return __uint_as_float(u << 16); }
__device__ __forceinline__ float bfhi(unsigned int u) { return __uint_as_float(u & 0xFFFF0000u); }
__device__ __forceinline__ float lrelu(float x) { return x > 0.f ? x : NEG * x; }

// ------------------------------- CSR build --------------------------------

__global__ __launch_bounds__(256) void k_init(int* deg, int* cur, int n) {
    int i = blockIdx.x * 256 + threadIdx.x;
    if (i < n) { deg[i] = 1; cur[i] = 0; }  // deg starts at 1 for self-loop
}

__global__ __launch_bounds__(256) void k_hist(const int* __restrict__ ei, int* deg, int E) {
    int e = blockIdx.x * 256 + threadIdx.x;
    if (e < E) atomicAdd(&deg[ei[E + e]], 1);   // dst = ei[1][e]
}

__global__ __launch_bounds__(1024) void k_scan(const int* __restrict__ deg, int* __restrict__ rowptr, int n) {
    __shared__ int sums[1024];
    int t = threadIdx.x;
    int chunk = (n + 1023) >> 10;
    int lo = t * chunk, hi = min(lo + chunk, n);
    int s = 0;
    for (int i = lo; i < hi; i++) s += deg[i];
    sums[t] = s;
    __syncthreads();
    for (int off = 1; off < 1024; off <<= 1) {
        int v = (t >= off) ? sums[t - off] : 0;
        __syncthreads();
        sums[t] += v;
        __syncthreads();
    }
    int run = sums[t] - s;  // exclusive prefix at lo
    for (int i = lo; i < hi; i++) { rowptr[i] = run; run += deg[i]; }
    if (t == 1023) rowptr[n] = sums[1023];
}

__global__ __launch_bounds__(256) void k_scatter(const int* __restrict__ ei, const int* __restrict__ rowptr,
                                                 int* cur, int* csr_src, int E, int N) {
    int e = blockIdx.x * 256 + threadIdx.x;
    if (e < E) {
        int d = ei[E + e];
        int pos = rowptr[d] + atomicAdd(&cur[d], 1);
        csr_src[pos] = ei[e];
    } else if (e < E + N) {
        int i = e - E;  // self loop
        int pos = rowptr[i] + atomicAdd(&cur[i], 1);
        csr_src[pos] = i;
    }
}

// ------------------------------- packing ----------------------------------

__global__ __launch_bounds__(256) void k_pack_split(const float* __restrict__ src,
                                                    unsigned short* __restrict__ hi,
                                                    unsigned short* __restrict__ lo, long n4) {
    long i = (long)blockIdx.x * 256 + threadIdx.x;
    long stride = (long)gridDim.x * 256;
    for (; i < n4; i += stride) {
        float4 v = ((const float4*)src)[i];
        unsigned short h0 = f2bf(v.x), h1 = f2bf(v.y), h2 = f2bf(v.z), h3 = f2bf(v.w);
        ushort4 H = make_ushort4(h0, h1, h2, h3);
        ushort4 L = make_ushort4(f2bf(v.x - bf2f(h0)), f2bf(v.y - bf2f(h1)),
                                 f2bf(v.z - bf2f(h2)), f2bf(v.w - bf2f(h3)));
        ((ushort4*)hi)[i] = H;
        ((ushort4*)lo)[i] = L;
    }
}

// W [K,N] fp32 -> WT hi/lo bf16 [N,K]
__global__ __launch_bounds__(256) void k_pack_wT(const float* __restrict__ W,
                                                 unsigned short* __restrict__ hiT,
                                                 unsigned short* __restrict__ loT, int K, int N) {
    int t = blockIdx.x * 256 + threadIdx.x;
    if (t >= K * N) return;
    int n = t / K, k = t - n * K;
    float v = W[(size_t)k * N + n];
    unsigned short h = f2bf(v);
    hiT[t] = h;
    loT[t] = f2bf(v - bf2f(h));
}

// ------------------------------- MFMA GEMM --------------------------------
// C[M,N] = A[M,K] @ B[K,N]; A hi/lo bf16 row-major, B hi/lo bf16 [N,K].
// Block = 4 waves = 64 rows x full N (N = 16*NF). Wave = 16 rows, NF
// independent 16x16 accumulators (ILP hides L2 latency); A fetched once.
template<int NF>
__global__ __launch_bounds__(256) void k_mfma_gemmT(const unsigned short* __restrict__ Ah,
                                                    const unsigned short* __restrict__ Al,
                                                    const unsigned short* __restrict__ BhT,
                                                    const unsigned short* __restrict__ BlT,
                                                    unsigned short* __restrict__ Cb, int M, int N, int K) {
    int wv = threadIdx.x >> 6, l = threadIdx.x & 63;
    int r = l & 15, hk = l >> 4;
    int m0 = blockIdx.x * 64 + wv * 16;
    int arow = min(m0 + r, M - 1);
    const unsigned short* aph = Ah + (size_t)arow * K + hk * 8;
    const unsigned short* apl = Al + (size_t)arow * K + hk * 8;
    const unsigned short* bph = BhT + (size_t)r * K + hk * 8;
    const unsigned short* bpl = BlT + (size_t)r * K + hk * 8;

    f32x4 acc[NF];
#pragma unroll
    for (int nf = 0; nf < NF; nf++) acc[nf] = f32x4{0, 0, 0, 0};

#pragma unroll 2
    for (int k0 = 0; k0 < K; k0 += 32) {
        bf16x8 ah = *(const bf16x8*)(aph + k0);
        bf16x8 al = *(const bf16x8*)(apl + k0);
#pragma unroll
        for (int nf = 0; nf < NF; nf++) {
            bf16x8 bh = *(const bf16x8*)(bph + (size_t)nf * 16 * K + k0);
            bf16x8 bl = *(const bf16x8*)(bpl + (size_t)nf * 16 * K + k0);
            acc[nf] = __builtin_amdgcn_mfma_f32_16x16x32_bf16(ah, bh, acc[nf], 0, 0, 0);
            acc[nf] = __builtin_amdgcn_mfma_f32_16x16x32_bf16(ah, bl, acc[nf], 0, 0, 0);
            acc[nf] = __builtin_amdgcn_mfma_f32_16x16x32_bf16(al, bh, acc[nf], 0, 0, 0);
        }
    }
#pragma unroll
    for (int nf = 0; nf < NF; nf++) {
#pragma unroll
        for (int j = 0; j < 4; j++) {
            int m = m0 + hk * 4 + j;
            if (m < M) Cb[(size_t)m * N + nf * 16 + r] = f2bf(acc[nf][j]);
        }
    }
}

// ------------------------------- attention --------------------------------

// a_src/a_dst[n,h] from bf16 xpb; H heads of C=64 channels, thread=(n,h)
__global__ __launch_bounds__(256) void k_attn(const unsigned short* __restrict__ xpb,
                                              const float* __restrict__ att_s,
                                              const float* __restrict__ att_d,
                                              float* __restrict__ as, float* __restrict__ ad,
                                              int M, int H) {
    int idx = blockIdx.x * 256 + threadIdx.x;
    if (idx >= M * H) return;
    int n = idx / H, h = idx - n * H;
    const uint4* row = (const uint4*)(xpb + (size_t)n * (64 * H) + h * 64);
    const float* fs = att_s + h * 64;
    const float* fd = att_d + h * 64;
    float s = 0.f, d = 0.f;
#pragma unroll
    for (int j = 0; j < 8; j++) {
        uint4 v = row[j];
        unsigned int uu[4] = {v.x, v.y, v.z, v.w};
#pragma unroll
        for (int q = 0; q < 4; q++) {
            float lo = bflo(uu[q]);
            float hi = bfhi(uu[q]);
            int c = j * 8 + q * 2;
            s += lo * fs[c] + hi * fs[c + 1];
            d += lo * fd[c] + hi * fd[c + 1];
        }
    }
    as[idx] = s; ad[idx] = d;
}

// gather layer 1: 1 wave/node, lane owns 4 cols (8B), head h=lane>>4.
// p computed inline from as/ad (no max-sub: raw is O(3), exp safe in fp32).
__global__ __launch_bounds__(256) void k_gather1(const unsigned short* __restrict__ xpb,
                                                 const float* __restrict__ as, const float* __restrict__ ad,
                                                 const int* __restrict__ rowptr, const int* __restrict__ csr_src,
                                                 const float* __restrict__ b1,
                                                 unsigned short* __restrict__ h1h, unsigned short* __restrict__ h1l,
                                                 int M) {
    int wv = threadIdx.x >> 6, lane = threadIdx.x & 63;
    int n = blockIdx.x * 4 + wv;
    if (n >= M) return;
    int h = lane >> 4;
    float adv = ad[n * 4 + h];
    int start = rowptr[n], end = rowptr[n + 1];
    float acc0[4] = {0.f, 0.f, 0.f, 0.f}, acc1[4] = {0.f, 0.f, 0.f, 0.f};
    float den0 = 0.f, den1 = 0.f;
    int e = start;
    for (; e + 1 < end; e += 2) {
        int s0 = csr_src[e], s1 = csr_src[e + 1];
        uint2 v0 = *(const uint2*)(xpb + (size_t)s0 * 256 + lane * 4);
        uint2 v1 = *(const uint2*)(xpb + (size_t)s1 * 256 + lane * 4);
        float p0 = __expf(lrelu(as[s0 * 4 + h] + adv));
        float p1 = __expf(lrelu(as[s1 * 4 + h] + adv));
        den0 += p0; den1 += p1;
        acc0[0] += p0 * bflo(v0.x); acc0[1] += p0 * bfhi(v0.x);
        acc0[2] += p0 * bflo(v0.y); acc0[3] += p0 * bfhi(v0.y);
        acc1[0] += p1 * bflo(v1.x); acc1[1] += p1 * bfhi(v1.x);
        acc1[2] += p1 * bflo(v1.y); acc1[3] += p1 * bfhi(v1.y);
    }
    if (e < end) {
        int s0 = csr_src[e];
        uint2 v0 = *(const uint2*)(xpb + (size_t)s0 * 256 + lane * 4);
        float p0 = __expf(lrelu(as[s0 * 4 + h] + adv));
        den0 += p0;
        acc0[0] += p0 * bflo(v0.x); acc0[1] += p0 * bfhi(v0.x);
        acc0[2] += p0 * bflo(v0.y); acc0[3] += p0 * bfhi(v0.y);
    }
    float dinv = 1.f / (den0 + den1 + 1e-16f);
    const float4 bb = *(const float4*)(b1 + lane * 4);
    float o0 = fmaxf((acc0[0] + acc1[0]) * dinv + bb.x, 0.f);
    float o1 = fmaxf((acc0[1] + acc1[1]) * dinv + bb.y, 0.f);
    float o2 = fmaxf((acc0[2] + acc1[2]) * dinv + bb.z, 0.f);
    float o3 = fmaxf((acc0[3] + acc1[3]) * dinv + bb.w, 0.f);
    unsigned short q0 = f2bf(o0), q1 = f2bf(o1), q2 = f2bf(o2), q3 = f2bf(o3);
    uint2 H, L;
    H.x = (unsigned)q0 | ((unsigned)q1 << 16);
    H.y = (unsigned)q2 | ((unsigned)q3 << 16);
    L.x = (unsigned)f2bf(o0 - bf2f(q0)) | ((unsigned)f2bf(o1 - bf2f(q1)) << 16);
    L.y = (unsigned)f2bf(o2 - bf2f(q2)) | ((unsigned)f2bf(o3 - bf2f(q3)) << 16);
    *(uint2*)(h1h + (size_t)n * 256 + lane * 4) = H;
    *(uint2*)(h1l + (size_t)n * 256 + lane * 4) = L;
}

// gather layer 2 (1 head, C=64): 1 wave/node, 4 edge-groups of 16 lanes,
// lane q=lane&15 owns 4 cols (8B). Fused uv = (h2+b2) . Wc halves.
__global__ __launch_bounds__(256) void k_gather2(const unsigned short* __restrict__ xp2b,
                                                 const float* __restrict__ as, const float* __restrict__ ad,
                                                 const int* __restrict__ rowptr, const int* __restrict__ csr_src,
                                                 const float* __restrict__ b2, const float* __restrict__ Wc,
                                                 float* __restrict__ uv, int M) {
    int wv = threadIdx.x >> 6, lane = threadIdx.x & 63;
    int n = blockIdx.x * 4 + wv;
    if (n >= M) return;
    int g = lane >> 4, q = lane & 15;
    float adv = ad[n];
    int start = rowptr[n], end = rowptr[n + 1];
    float acc[4] = {0.f, 0.f, 0.f, 0.f};
    float den = 0.f;
    for (int e = start; e < end; e += 4) {
        int ee = e + g;
        bool ok = ee < end;
        int s = csr_src[ok ? ee : start];
        uint2 v = *(const uint2*)(xp2b + (size_t)s * 64 + q * 4);
        float pw = ok ? __expf(lrelu(as[s] + adv)) : 0.f;
        den += pw;
        acc[0] += pw * bflo(v.x); acc[1] += pw * bfhi(v.x);
        acc[2] += pw * bflo(v.y); acc[3] += pw * bfhi(v.y);
    }
#pragma unroll
    for (int j = 0; j < 4; j++) {
        acc[j] += __shfl_xor(acc[j], 16, 64);
        acc[j] += __shfl_xor(acc[j], 32, 64);
    }
    den += __shfl_xor(den, 16, 64);
    den += __shfl_xor(den, 32, 64);
    float dinv = 1.f / (den + 1e-16f);
    float pr[8] = {0.f, 0.f, 0.f, 0.f, 0.f, 0.f, 0.f, 0.f};
#pragma unroll
    for (int j = 0; j < 4; j++) {
        int c = q * 4 + j;
        float val = acc[j] * dinv + b2[c];
#pragma unroll
        for (int k = 0; k < 4; k++) {
            pr[k]     += val * Wc[c * 4 + k];
            pr[4 + k] += val * Wc[(64 + c) * 4 + k];
        }
    }
#pragma unroll
    for (int off = 1; off <= 8; off <<= 1)
#pragma unroll
        for (int j = 0; j < 8; j++) pr[j] += __shfl_xor(pr[j], off, 64);
    if (lane == 0) {
        float4* o = (float4*)(uv + (size_t)n * 8);
        o[0] = make_float4(pr[0], pr[1], pr[2], pr[3]);
        o[1] = make_float4(pr[4], pr[5], pr[6], pr[7]);
    }
}

__global__ __launch_bounds__(256) void k_classify(const int* __restrict__ ei, const float* __restrict__ uv,
                                                  const float* __restrict__ bc, float* __restrict__ out, int E) {
    int e = blockIdx.x * 256 + threadIdx.x;
    if (e >= E) return;
    int r = ei[e];
    int c = ei[E + e];
    float4 u = *(const float4*)(uv + (size_t)r * 8);
    float4 v = *(const float4*)(uv + (size_t)c * 8 + 4);
    float4 o;
    o.x = u.x + v.x + bc[0];
    o.y = u.y + v.y + bc[1];
    o.z = u.z + v.z + bc[2];
    o.w = u.w + v.w + bc[3];
    *(float4*)(out + (size_t)e * 4) = o;
}

// ---------------------------------------------------------------------------

extern "C" void kernel_launch(void* const* d_in, const int* in_sizes, int n_in,
                              void* d_out, int out_size, void* d_ws, size_t ws_size,
                              hipStream_t stream) {
    const float* x    = (const float*)d_in[0];
    const int*   ei   = (const int*)d_in[1];
    // d_in[2] = w (edge weights) ignored by reference
    const float* W1   = (const float*)d_in[3];
    const float* atS1 = (const float*)d_in[4];
    const float* atD1 = (const float*)d_in[5];
    const float* b1   = (const float*)d_in[6];
    const float* W2   = (const float*)d_in[7];
    const float* atS2 = (const float*)d_in[8];
    const float* atD2 = (const float*)d_in[9];
    const float* b2   = (const float*)d_in[10];
    const float* Wc   = (const float*)d_in[11];
    const float* bc   = (const float*)d_in[12];
    float* out = (float*)d_out;

    const int N = in_sizes[0] / 256;
    const int E = in_sizes[1] / 2;
    const int Etot = E + N;

    char* w = (char*)d_ws;
    size_t off = 0;
    auto alloc = [&](size_t b) { size_t o = off; off = (o + b + 255) & ~(size_t)255; return o; };
    size_t oXH  = alloc((size_t)N * 256 * 2);   // x hi split; later h1h
    size_t oXL  = alloc((size_t)N * 256 * 2);   // x lo split; later h1l
    size_t oXPB = alloc((size_t)N * 256 * 2);   // xp bf16; later xp2b|uv
    size_t oAS1 = alloc((size_t)N * 4 * 4);
    size_t oAD1 = alloc((size_t)N * 4 * 4);
    size_t oDEG = alloc((size_t)N * 4);
    size_t oCUR = alloc((size_t)N * 4);
    size_t oRP  = alloc((size_t)(N + 1) * 4);
    size_t oCSR = alloc((size_t)Etot * 4);
    size_t oW1H = alloc((size_t)256 * 256 * 2);
    size_t oW1L = alloc((size_t)256 * 256 * 2);
    size_t oW2H = alloc((size_t)256 * 64 * 2);
    size_t oW2L = alloc((size_t)256 * 64 * 2);
    (void)ws_size;

    unsigned short* xh   = (unsigned short*)(w + oXH);
    unsigned short* xl   = (unsigned short*)(w + oXL);
    unsigned short* h1h  = (unsigned short*)(w + oXH);   // alias: xh dead after gemm1
    unsigned short* h1l  = (unsigned short*)(w + oXL);
    unsigned short* xpb  = (unsigned short*)(w + oXPB);
    unsigned short* xp2b = (unsigned short*)(w + oXPB);  // alias: xpb dead after gather1
    float* uv  = (float*)(w + oXPB + (size_t)N * 64 * 2 + 256);
    uv = (float*)(((uintptr_t)uv + 255) & ~(uintptr_t)255);
    float* as1 = (float*)(w + oAS1);
    float* ad1 = (float*)(w + oAD1);
    float* as2 = (float*)(w + oAS1);                     // alias: as1 dead after gather1
    float* ad2 = (float*)(w + oAD1);
    int* deg    = (int*)(w + oDEG);
    int* cur    = (int*)(w + oCUR);
    int* rowptr = (int*)(w + oRP);
    int* csr    = (int*)(w + oCSR);
    unsigned short* W1hT = (unsigned short*)(w + oW1H);
    unsigned short* W1lT = (unsigned short*)(w + oW1L);
    unsigned short* W2hT = (unsigned short*)(w + oW2H);
    unsigned short* W2lT = (unsigned short*)(w + oW2L);

    // CSR build
    k_init<<<(N + 255) / 256, 256, 0, stream>>>(deg, cur, N);
    k_hist<<<(E + 255) / 256, 256, 0, stream>>>(ei, deg, E);
    k_scan<<<1, 1024, 0, stream>>>(deg, rowptr, N);
    k_scatter<<<(Etot + 255) / 256, 256, 0, stream>>>(ei, rowptr, cur, csr, E, N);

    // packing
    k_pack_split<<<2048, 256, 0, stream>>>(x, xh, xl, (long)N * 64);
    k_pack_wT<<<(256 * 256 + 255) / 256, 256, 0, stream>>>(W1, W1hT, W1lT, 256, 256);
    k_pack_wT<<<(256 * 64 + 255) / 256, 256, 0, stream>>>(W2, W2hT, W2lT, 256, 64);

    // Layer 1
    k_mfma_gemmT<16><<<(N + 63) / 64, 256, 0, stream>>>(xh, xl, W1hT, W1lT, xpb, N, 256, 256);
    k_attn<<<(N * 4 + 255) / 256, 256, 0, stream>>>(xpb, atS1, atD1, as1, ad1, N, 4);
    k_gather1<<<(N + 3) / 4, 256, 0, stream>>>(xpb, as1, ad1, rowptr, csr, b1, h1h, h1l, N);

    // Layer 2
    k_mfma_gemmT<4><<<(N + 63) / 64, 256, 0, stream>>>(h1h, h1l, W2hT, W2lT, xp2b, N, 64, 256);
    k_attn<<<(N + 255) / 256, 256, 0, stream>>>(xp2b, atS2, atD2, as2, ad2, N, 1);
    k_gather2<<<(N + 3) / 4, 256, 0, stream>>>(xp2b, as2, ad2, rowptr, csr, b2, Wc, uv, N);

    // Edge classifier
    k_classify<<<(E + 255) / 256, 256, 0, stream>>>(ei, uv, bc, out, E);
}

// Round 6
// 490.550 us; speedup vs baseline: 1.0413x; 1.0413x over previous
//
#include <hip/hip_runtime.h>

// ---------------------------------------------------------------------------
// GAT edge classifier, MI355X.
//   CSR build (deg hist -> scan -> scatter)            [int atomics only]
//   pack: x -> (xh, xl) bf16 split; W1,W2 -> transposed bf16 splits
//   GEMM  (templated NF): block = 4 waves x 64 rows, wave = 16 rows x 16*NF
//         cols, grid.y splits N. launch_bounds(256,4) -> 128 VGPR so B-loads
//         pipeline across nf and unrolled K-chunks. 3-term bf16 split.
//   attn node dots (bf16 reads)
//   gather1: 1 wave/node, 8B/lane, fused p=exp(lrelu(.)), 2-edge ILP
//   GEMM2 -> xp2b; attn2; gather2 (4-edge groups/wave, fused uv=h2@Wc)
//   classify: out[e] = u[row] + v[col] + bc
// ---------------------------------------------------------------------------

#define NEG 0.2f

typedef __attribute__((ext_vector_type(8))) short bf16x8;
typedef __attribute__((ext_vector_type(4))) float f32x4;

__device__ __forceinline__ unsigned short f2bf(float f) {
    unsigned int u = __float_as_uint(f);
    unsigned int r = (u + 0x7FFFu + ((u >> 16) & 1u)) >> 16;   // RNE
    return (unsigned short)r;
}
__device__ __forceinline__ float bf2f(unsigned short h) {
    return __uint_as_float(((unsigned int)h) << 16);
}
__device__ __forceinline__ float bflo(unsigned int u) { return __uint_as_float(u << 16); }
__device__ __forceinline__ float bfhi(unsigned int u) { return __uint_as_float(u & 0xFFFF0000u); }
__device__ __forceinline__ float lrelu(float x) { return x > 0.f ? x : NEG * x; }

// ------------------------------- CSR build --------------------------------

__global__ __launch_bounds__(256) void k_init(int* deg, int* cur, int n) {
    int i = blockIdx.x * 256 + threadIdx.x;
    if (i < n) { deg[i] = 1; cur[i] = 0; }  // deg starts at 1 for self-loop
}

__global__ __launch_bounds__(256) void k_hist(const int* __restrict__ ei, int* deg, int E) {
    int e = blockIdx.x * 256 + threadIdx.x;
    if (e < E) atomicAdd(&deg[ei[E + e]], 1);   // dst = ei[1][e]
}

__global__ __launch_bounds__(1024) void k_scan(const int* __restrict__ deg, int* __restrict__ rowptr, int n) {
    __shared__ int sums[1024];
    int t = threadIdx.x;
    int chunk = (n + 1023) >> 10;
    int lo = t * chunk, hi = min(lo + chunk, n);
    int s = 0;
    for (int i = lo; i < hi; i++) s += deg[i];
    sums[t] = s;
    __syncthreads();
    for (int off = 1; off < 1024; off <<= 1) {
        int v = (t >= off) ? sums[t - off] : 0;
        __syncthreads();
        sums[t] += v;
        __syncthreads();
    }
    int run = sums[t] - s;  // exclusive prefix at lo
    for (int i = lo; i < hi; i++) { rowptr[i] = run; run += deg[i]; }
    if (t == 1023) rowptr[n] = sums[1023];
}

__global__ __launch_bounds__(256) void k_scatter(const int* __restrict__ ei, const int* __restrict__ rowptr,
                                                 int* cur, int* csr_src, int E, int N) {
    int e = blockIdx.x * 256 + threadIdx.x;
    if (e < E) {
        int d = ei[E + e];
        int pos = rowptr[d] + atomicAdd(&cur[d], 1);
        csr_src[pos] = ei[e];
    } else if (e < E + N) {
        int i = e - E;  // self loop
        int pos = rowptr[i] + atomicAdd(&cur[i], 1);
        csr_src[pos] = i;
    }
}

// ------------------------------- packing ----------------------------------

__global__ __launch_bounds__(256) void k_pack_split(const float* __restrict__ src,
                                                    unsigned short* __restrict__ hi,
                                                    unsigned short* __restrict__ lo, long n4) {
    long i = (long)blockIdx.x * 256 + threadIdx.x;
    long stride = (long)gridDim.x * 256;
    for (; i < n4; i += stride) {
        float4 v = ((const float4*)src)[i];
        unsigned short h0 = f2bf(v.x), h1 = f2bf(v.y), h2 = f2bf(v.z), h3 = f2bf(v.w);
        ushort4 H = make_ushort4(h0, h1, h2, h3);
        ushort4 L = make_ushort4(f2bf(v.x - bf2f(h0)), f2bf(v.y - bf2f(h1)),
                                 f2bf(v.z - bf2f(h2)), f2bf(v.w - bf2f(h3)));
        ((ushort4*)hi)[i] = H;
        ((ushort4*)lo)[i] = L;
    }
}

// W [K,N] fp32 -> WT hi/lo bf16 [N,K]
__global__ __launch_bounds__(256) void k_pack_wT(const float* __restrict__ W,
                                                 unsigned short* __restrict__ hiT,
                                                 unsigned short* __restrict__ loT, int K, int N) {
    int t = blockIdx.x * 256 + threadIdx.x;
    if (t >= K * N) return;
    int n = t / K, k = t - n * K;
    float v = W[(size_t)k * N + n];
    unsigned short h = f2bf(v);
    hiT[t] = h;
    loT[t] = f2bf(v - bf2f(h));
}

// ------------------------------- MFMA GEMM --------------------------------
// C[M,N] = A[M,K] @ B[K,N]; A hi/lo bf16 row-major, B hi/lo bf16 [N,K].
// Block = 4 waves = 64 rows x 16*NF cols; grid.y tiles N. Wave = 16 rows,
// NF independent 16x16 accumulators. launch_bounds(256,4) -> 128 VGPR so
// the compiler keeps several nf's B operands + next chunks in flight
// (round-5 failure: 68 VGPR forced load->wait->mfma serialization).
template<int NF>
__global__ __launch_bounds__(256, 4) void k_mfma_gemmT(const unsigned short* __restrict__ Ah,
                                                       const unsigned short* __restrict__ Al,
                                                       const unsigned short* __restrict__ BhT,
                                                       const unsigned short* __restrict__ BlT,
                                                       unsigned short* __restrict__ Cb, int M, int N, int K) {
    int wv = threadIdx.x >> 6, l = threadIdx.x & 63;
    int r = l & 15, hk = l >> 4;
    int m0 = blockIdx.x * 64 + wv * 16;
    int n0 = blockIdx.y * (16 * NF);
    int arow = min(m0 + r, M - 1);
    const unsigned short* aph = Ah + (size_t)arow * K + hk * 8;
    const unsigned short* apl = Al + (size_t)arow * K + hk * 8;
    const unsigned short* bph = BhT + (size_t)(n0 + r) * K + hk * 8;
    const unsigned short* bpl = BlT + (size_t)(n0 + r) * K + hk * 8;

    f32x4 acc[NF];
#pragma unroll
    for (int nf = 0; nf < NF; nf++) acc[nf] = f32x4{0, 0, 0, 0};

#pragma unroll 4
    for (int k0 = 0; k0 < K; k0 += 32) {
        bf16x8 ah = *(const bf16x8*)(aph + k0);
        bf16x8 al = *(const bf16x8*)(apl + k0);
#pragma unroll
        for (int nf = 0; nf < NF; nf++) {
            bf16x8 bh = *(const bf16x8*)(bph + (size_t)nf * 16 * K + k0);
            bf16x8 bl = *(const bf16x8*)(bpl + (size_t)nf * 16 * K + k0);
            acc[nf] = __builtin_amdgcn_mfma_f32_16x16x32_bf16(ah, bh, acc[nf], 0, 0, 0);
            acc[nf] = __builtin_amdgcn_mfma_f32_16x16x32_bf16(ah, bl, acc[nf], 0, 0, 0);
            acc[nf] = __builtin_amdgcn_mfma_f32_16x16x32_bf16(al, bh, acc[nf], 0, 0, 0);
        }
    }
#pragma unroll
    for (int nf = 0; nf < NF; nf++) {
#pragma unroll
        for (int j = 0; j < 4; j++) {
            int m = m0 + hk * 4 + j;
            if (m < M) Cb[(size_t)m * N + n0 + nf * 16 + r] = f2bf(acc[nf][j]);
        }
    }
}

// ------------------------------- attention --------------------------------

// a_src/a_dst[n,h] from bf16 xpb; H heads of C=64 channels, thread=(n,h)
__global__ __launch_bounds__(256) void k_attn(const unsigned short* __restrict__ xpb,
                                              const float* __restrict__ att_s,
                                              const float* __restrict__ att_d,
                                              float* __restrict__ as, float* __restrict__ ad,
                                              int M, int H) {
    int idx = blockIdx.x * 256 + threadIdx.x;
    if (idx >= M * H) return;
    int n = idx / H, h = idx - n * H;
    const uint4* row = (const uint4*)(xpb + (size_t)n * (64 * H) + h * 64);
    const float* fs = att_s + h * 64;
    const float* fd = att_d + h * 64;
    float s = 0.f, d = 0.f;
#pragma unroll
    for (int j = 0; j < 8; j++) {
        uint4 v = row[j];
        unsigned int uu[4] = {v.x, v.y, v.z, v.w};
#pragma unroll
        for (int q = 0; q < 4; q++) {
            float lo = bflo(uu[q]);
            float hi = bfhi(uu[q]);
            int c = j * 8 + q * 2;
            s += lo * fs[c] + hi * fs[c + 1];
            d += lo * fd[c] + hi * fd[c + 1];
        }
    }
    as[idx] = s; ad[idx] = d;
}

// gather layer 1: 1 wave/node, lane owns 4 cols (8B), head h=lane>>4.
// p computed inline from as/ad (no max-sub: raw is O(3), exp safe in fp32).
__global__ __launch_bounds__(256) void k_gather1(const unsigned short* __restrict__ xpb,
                                                 const float* __restrict__ as, const float* __restrict__ ad,
                                                 const int* __restrict__ rowptr, const int* __restrict__ csr_src,
                                                 const float* __restrict__ b1,
                                                 unsigned short* __restrict__ h1h, unsigned short* __restrict__ h1l,
                                                 int M) {
    int wv = threadIdx.x >> 6, lane = threadIdx.x & 63;
    int n = blockIdx.x * 4 + wv;
    if (n >= M) return;
    int h = lane >> 4;
    float adv = ad[n * 4 + h];
    int start = rowptr[n], end = rowptr[n + 1];
    float acc0[4] = {0.f, 0.f, 0.f, 0.f}, acc1[4] = {0.f, 0.f, 0.f, 0.f};
    float den0 = 0.f, den1 = 0.f;
    int e = start;
    for (; e + 1 < end; e += 2) {
        int s0 = csr_src[e], s1 = csr_src[e + 1];
        uint2 v0 = *(const uint2*)(xpb + (size_t)s0 * 256 + lane * 4);
        uint2 v1 = *(const uint2*)(xpb + (size_t)s1 * 256 + lane * 4);
        float p0 = __expf(lrelu(as[s0 * 4 + h] + adv));
        float p1 = __expf(lrelu(as[s1 * 4 + h] + adv));
        den0 += p0; den1 += p1;
        acc0[0] += p0 * bflo(v0.x); acc0[1] += p0 * bfhi(v0.x);
        acc0[2] += p0 * bflo(v0.y); acc0[3] += p0 * bfhi(v0.y);
        acc1[0] += p1 * bflo(v1.x); acc1[1] += p1 * bfhi(v1.x);
        acc1[2] += p1 * bflo(v1.y); acc1[3] += p1 * bfhi(v1.y);
    }
    if (e < end) {
        int s0 = csr_src[e];
        uint2 v0 = *(const uint2*)(xpb + (size_t)s0 * 256 + lane * 4);
        float p0 = __expf(lrelu(as[s0 * 4 + h] + adv));
        den0 += p0;
        acc0[0] += p0 * bflo(v0.x); acc0[1] += p0 * bfhi(v0.x);
        acc0[2] += p0 * bflo(v0.y); acc0[3] += p0 * bfhi(v0.y);
    }
    float dinv = 1.f / (den0 + den1 + 1e-16f);
    const float4 bb = *(const float4*)(b1 + lane * 4);
    float o0 = fmaxf((acc0[0] + acc1[0]) * dinv + bb.x, 0.f);
    float o1 = fmaxf((acc0[1] + acc1[1]) * dinv + bb.y, 0.f);
    float o2 = fmaxf((acc0[2] + acc1[2]) * dinv + bb.z, 0.f);
    float o3 = fmaxf((acc0[3] + acc1[3]) * dinv + bb.w, 0.f);
    unsigned short q0 = f2bf(o0), q1 = f2bf(o1), q2 = f2bf(o2), q3 = f2bf(o3);
    uint2 H, L;
    H.x = (unsigned)q0 | ((unsigned)q1 << 16);
    H.y = (unsigned)q2 | ((unsigned)q3 << 16);
    L.x = (unsigned)f2bf(o0 - bf2f(q0)) | ((unsigned)f2bf(o1 - bf2f(q1)) << 16);
    L.y = (unsigned)f2bf(o2 - bf2f(q2)) | ((unsigned)f2bf(o3 - bf2f(q3)) << 16);
    *(uint2*)(h1h + (size_t)n * 256 + lane * 4) = H;
    *(uint2*)(h1l + (size_t)n * 256 + lane * 4) = L;
}

// gather layer 2 (1 head, C=64): 1 wave/node, 4 edge-groups of 16 lanes,
// lane q=lane&15 owns 4 cols (8B). Fused uv = (h2+b2) . Wc halves.
__global__ __launch_bounds__(256) void k_gather2(const unsigned short* __restrict__ xp2b,
                                                 const float* __restrict__ as, const float* __restrict__ ad,
                                                 const int* __restrict__ rowptr, const int* __restrict__ csr_src,
                                                 const float* __restrict__ b2, const float* __restrict__ Wc,
                                                 float* __restrict__ uv, int M) {
    int wv = threadIdx.x >> 6, lane = threadIdx.x & 63;
    int n = blockIdx.x * 4 + wv;
    if (n >= M) return;
    int g = lane >> 4, q = lane & 15;
    float adv = ad[n];
    int start = rowptr[n], end = rowptr[n + 1];
    float acc[4] = {0.f, 0.f, 0.f, 0.f};
    float den = 0.f;
    for (int e = start; e < end; e += 4) {
        int ee = e + g;
        bool ok = ee < end;
        int s = csr_src[ok ? ee : start];
        uint2 v = *(const uint2*)(xp2b + (size_t)s * 64 + q * 4);
        float pw = ok ? __expf(lrelu(as[s] + adv)) : 0.f;
        den += pw;
        acc[0] += pw * bflo(v.x); acc[1] += pw * bfhi(v.x);
        acc[2] += pw * bflo(v.y); acc[3] += pw * bfhi(v.y);
    }
#pragma unroll
    for (int j = 0; j < 4; j++) {
        acc[j] += __shfl_xor(acc[j], 16, 64);
        acc[j] += __shfl_xor(acc[j], 32, 64);
    }
    den += __shfl_xor(den, 16, 64);
    den += __shfl_xor(den, 32, 64);
    float dinv = 1.f / (den + 1e-16f);
    float pr[8] = {0.f, 0.f, 0.f, 0.f, 0.f, 0.f, 0.f, 0.f};
#pragma unroll
    for (int j = 0; j < 4; j++) {
        int c = q * 4 + j;
        float val = acc[j] * dinv + b2[c];
#pragma unroll
        for (int k = 0; k < 4; k++) {
            pr[k]     += val * Wc[c * 4 + k];
            pr[4 + k] += val * Wc[(64 + c) * 4 + k];
        }
    }
#pragma unroll
    for (int off = 1; off <= 8; off <<= 1)
#pragma unroll
        for (int j = 0; j < 8; j++) pr[j] += __shfl_xor(pr[j], off, 64);
    if (lane == 0) {
        float4* o = (float4*)(uv + (size_t)n * 8);
        o[0] = make_float4(pr[0], pr[1], pr[2], pr[3]);
        o[1] = make_float4(pr[4], pr[5], pr[6], pr[7]);
    }
}

__global__ __launch_bounds__(256) void k_classify(const int* __restrict__ ei, const float* __restrict__ uv,
                                                  const float* __restrict__ bc, float* __restrict__ out, int E) {
    int e = blockIdx.x * 256 + threadIdx.x;
    if (e >= E) return;
    int r = ei[e];
    int c = ei[E + e];
    float4 u = *(const float4*)(uv + (size_t)r * 8);
    float4 v = *(const float4*)(uv + (size_t)c * 8 + 4);
    float4 o;
    o.x = u.x + v.x + bc[0];
    o.y = u.y + v.y + bc[1];
    o.z = u.z + v.z + bc[2];
    o.w = u.w + v.w + bc[3];
    *(float4*)(out + (size_t)e * 4) = o;
}

// ---------------------------------------------------------------------------

extern "C" void kernel_launch(void* const* d_in, const int* in_sizes, int n_in,
                              void* d_out, int out_size, void* d_ws, size_t ws_size,
                              hipStream_t stream) {
    const float* x    = (const float*)d_in[0];
    const int*   ei   = (const int*)d_in[1];
    // d_in[2] = w (edge weights) ignored by reference
    const float* W1   = (const float*)d_in[3];
    const float* atS1 = (const float*)d_in[4];
    const float* atD1 = (const float*)d_in[5];
    const float* b1   = (const float*)d_in[6];
    const float* W2   = (const float*)d_in[7];
    const float* atS2 = (const float*)d_in[8];
    const float* atD2 = (const float*)d_in[9];
    const float* b2   = (const float*)d_in[10];
    const float* Wc   = (const float*)d_in[11];
    const float* bc   = (const float*)d_in[12];
    float* out = (float*)d_out;

    const int N = in_sizes[0] / 256;
    const int E = in_sizes[1] / 2;
    const int Etot = E + N;

    char* w = (char*)d_ws;
    size_t off = 0;
    auto alloc = [&](size_t b) { size_t o = off; off = (o + b + 255) & ~(size_t)255; return o; };
    size_t oXH  = alloc((size_t)N * 256 * 2);   // x hi split; later h1h
    size_t oXL  = alloc((size_t)N * 256 * 2);   // x lo split; later h1l
    size_t oXPB = alloc((size_t)N * 256 * 2);   // xp bf16; later xp2b|uv
    size_t oAS1 = alloc((size_t)N * 4 * 4);
    size_t oAD1 = alloc((size_t)N * 4 * 4);
    size_t oDEG = alloc((size_t)N * 4);
    size_t oCUR = alloc((size_t)N * 4);
    size_t oRP  = alloc((size_t)(N + 1) * 4);
    size_t oCSR = alloc((size_t)Etot * 4);
    size_t oW1H = alloc((size_t)256 * 256 * 2);
    size_t oW1L = alloc((size_t)256 * 256 * 2);
    size_t oW2H = alloc((size_t)256 * 64 * 2);
    size_t oW2L = alloc((size_t)256 * 64 * 2);
    (void)ws_size;

    unsigned short* xh   = (unsigned short*)(w + oXH);
    unsigned short* xl   = (unsigned short*)(w + oXL);
    unsigned short* h1h  = (unsigned short*)(w + oXH);   // alias: xh dead after gemm1
    unsigned short* h1l  = (unsigned short*)(w + oXL);
    unsigned short* xpb  = (unsigned short*)(w + oXPB);
    unsigned short* xp2b = (unsigned short*)(w + oXPB);  // alias: xpb dead after gather1
    float* uv  = (float*)(w + oXPB + (size_t)N * 64 * 2 + 256);
    uv = (float*)(((uintptr_t)uv + 255) & ~(uintptr_t)255);
    float* as1 = (float*)(w + oAS1);
    float* ad1 = (float*)(w + oAD1);
    float* as2 = (float*)(w + oAS1);                     // alias: as1 dead after gather1
    float* ad2 = (float*)(w + oAD1);
    int* deg    = (int*)(w + oDEG);
    int* cur    = (int*)(w + oCUR);
    int* rowptr = (int*)(w + oRP);
    int* csr    = (int*)(w + oCSR);
    unsigned short* W1hT = (unsigned short*)(w + oW1H);
    unsigned short* W1lT = (unsigned short*)(w + oW1L);
    unsigned short* W2hT = (unsigned short*)(w + oW2H);
    unsigned short* W2lT = (unsigned short*)(w + oW2L);

    // CSR build
    k_init<<<(N + 255) / 256, 256, 0, stream>>>(deg, cur, N);
    k_hist<<<(E + 255) / 256, 256, 0, stream>>>(ei, deg, E);
    k_scan<<<1, 1024, 0, stream>>>(deg, rowptr, N);
    k_scatter<<<(Etot + 255) / 256, 256, 0, stream>>>(ei, rowptr, cur, csr, E, N);

    // packing
    k_pack_split<<<2048, 256, 0, stream>>>(x, xh, xl, (long)N * 64);
    k_pack_wT<<<(256 * 256 + 255) / 256, 256, 0, stream>>>(W1, W1hT, W1lT, 256, 256);
    k_pack_wT<<<(256 * 64 + 255) / 256, 256, 0, stream>>>(W2, W2hT, W2lT, 256, 64);

    // Layer 1: NF=8, grid.y=2 (wave covers 16 rows x 128 cols)
    {
        dim3 g((N + 63) / 64, 2);
        k_mfma_gemmT<8><<<g, 256, 0, stream>>>(xh, xl, W1hT, W1lT, xpb, N, 256, 256);
    }
    k_attn<<<(N * 4 + 255) / 256, 256, 0, stream>>>(xpb, atS1, atD1, as1, ad1, N, 4);
    k_gather1<<<(N + 3) / 4, 256, 0, stream>>>(xpb, as1, ad1, rowptr, csr, b1, h1h, h1l, N);

    // Layer 2: NF=4, grid.y=1
    {
        dim3 g((N + 63) / 64, 1);
        k_mfma_gemmT<4><<<g, 256, 0, stream>>>(h1h, h1l, W2hT, W2lT, xp2b, N, 64, 256);
    }
    k_attn<<<(N + 255) / 256, 256, 0, stream>>>(xp2b, atS2, atD2, as2, ad2, N, 1);
    k_gather2<<<(N + 3) / 4, 256, 0, stream>>>(xp2b, as2, ad2, rowptr, csr, b2, Wc, uv, N);

    // Edge classifier
    k_classify<<<(E + 255) / 256, 256, 0, stream>>>(ei, uv, bc, out, E);
}